// Round 1
// 239.837 us; speedup vs baseline: 1.0912x; 1.0912x over previous
//
#include <hip/hip_runtime.h>

typedef unsigned short ushort_t;
typedef unsigned int uint_t;
typedef __attribute__((ext_vector_type(8))) short short8;
typedef __attribute__((ext_vector_type(4))) float floatx4;

#define S_LEN 2048
#define D_DIM 1024
#define H_NUM 16
#define HD 64

__device__ __forceinline__ float bf2f(ushort_t u) {
    union { uint_t i; float f; } c; c.i = ((uint_t)u) << 16; return c.f;
}
__device__ __forceinline__ ushort_t f2bf(float f) {
    union { float f; uint_t i; } c; c.f = f;
    uint_t r = c.i + 0x7fffu + ((c.i >> 16) & 1u);
    return (ushort_t)(r >> 16);
}

// ---------------------------------------------------------------- cast x
__global__ __launch_bounds__(256, 4) void cast_x_kernel(
        const float* __restrict__ in, ushort_t* __restrict__ out) {
    const int idx = (blockIdx.x * 256 + threadIdx.x) * 4;
    const float4 v = *(const float4*)(in + idx);
    ushort4 o;
    o.x = f2bf(v.x); o.y = f2bf(v.y); o.z = f2bf(v.z); o.w = f2bf(v.w);
    *(ushort4*)(out + idx) = o;
}

// ---------------------------------------------------------------- transpose+cast (validated R3)
__global__ __launch_bounds__(256, 2) void transpose4_kernel(
        const float* __restrict__ W0, const float* __restrict__ W1,
        const float* __restrict__ W2, const float* __restrict__ W3,
        ushort_t* __restrict__ T0, ushort_t* __restrict__ T1,
        ushort_t* __restrict__ T2, ushort_t* __restrict__ T3) {
    const int z = blockIdx.z;
    const float* in  = (z == 0) ? W0 : (z == 1) ? W1 : (z == 2) ? W2 : W3;
    ushort_t*    out = (z == 0) ? T0 : (z == 1) ? T1 : (z == 2) ? T2 : T3;
    __shared__ __align__(16) ushort_t t[64][65];
    const int r0 = blockIdx.y * 64, c0 = blockIdx.x * 64;
    const int tr = threadIdx.x >> 4;
    const int tc = (threadIdx.x & 15) * 4;
#pragma unroll
    for (int i = 0; i < 4; ++i) {
        const int row = tr + i * 16;
        const float4 v = *(const float4*)(in + (size_t)(r0 + row) * D_DIM + c0 + tc);
        t[row][tc + 0] = f2bf(v.x); t[row][tc + 1] = f2bf(v.y);
        t[row][tc + 2] = f2bf(v.z); t[row][tc + 3] = f2bf(v.w);
    }
    __syncthreads();
#pragma unroll
    for (int i = 0; i < 4; ++i) {
        const int n = tr + i * 16;
        ushort4 v;
        v.x = t[tc + 0][n]; v.y = t[tc + 1][n];
        v.z = t[tc + 2][n]; v.w = t[tc + 3][n];
        *(ushort4*)(out + (size_t)(c0 + n) * D_DIM + r0 + tc) = v;
    }
}

// ---------------------------------------------------------------- MFMA GEMM tile (validated R3)
// C[M,N] = A[M,K] @ B with BT = B^T [N,K] row-major. 128x128 tile, BK=32,
// 4 waves 2x2 of 64x64, 16x16x32 bf16 MFMA, register->LDS staging.
__device__ __forceinline__ void gemm_tile(
        const ushort_t* __restrict__ A, const ushort_t* __restrict__ BT,
        const int m0, const int n0,
        ushort_t* As, ushort_t* Bs, floatx4 acc[4][4]) {
    const int tid  = threadIdx.x;
    const int w    = tid >> 6;
    const int wm   = (w >> 1) * 64;
    const int wn   = (w & 1) * 64;
    const int lrow = tid & 15;
    const int kq   = ((tid & 63) >> 4) * 8;

    const int flat0 = tid * 8;
    const int flat1 = (256 + tid) * 8;
    const int row0 = flat0 >> 5, kk0 = flat0 & 31;
    const int row1 = flat1 >> 5, kk1 = flat1 & 31;

    for (int k0 = 0; k0 < D_DIM; k0 += 32) {
        const short8 a0 = *(const short8*)(A  + (size_t)(m0 + row0) * D_DIM + k0 + kk0);
        const short8 b0 = *(const short8*)(BT + (size_t)(n0 + row0) * D_DIM + k0 + kk0);
        const short8 a1 = *(const short8*)(A  + (size_t)(m0 + row1) * D_DIM + k0 + kk1);
        const short8 b1 = *(const short8*)(BT + (size_t)(n0 + row1) * D_DIM + k0 + kk1);
        __syncthreads();
        *(short8*)(As + flat0) = a0; *(short8*)(Bs + flat0) = b0;
        *(short8*)(As + flat1) = a1; *(short8*)(Bs + flat1) = b1;
        __syncthreads();

        short8 av[4], bv[4];
#pragma unroll
        for (int i = 0; i < 4; ++i)
            av[i] = *(const short8*)(As + (wm + i * 16 + lrow) * 32 + kq);
#pragma unroll
        for (int j = 0; j < 4; ++j)
            bv[j] = *(const short8*)(Bs + (wn + j * 16 + lrow) * 32 + kq);
#pragma unroll
        for (int i = 0; i < 4; ++i)
#pragma unroll
            for (int j = 0; j < 4; ++j)
                acc[i][j] = __builtin_amdgcn_mfma_f32_16x16x32_bf16(
                    av[i], bv[j], acc[i][j], 0, 0, 0);
    }
}

// QKV: z picks weight/dest; writes merged row-major [B*S, D] bf16.
__global__ __launch_bounds__(256, 2) void gemm_qkv_kernel(
        const ushort_t* __restrict__ A,
        const ushort_t* __restrict__ WqT, const ushort_t* __restrict__ WkT,
        const ushort_t* __restrict__ WvT,
        ushort_t* __restrict__ Qo, ushort_t* __restrict__ Ko,
        ushort_t* __restrict__ Vo) {
    const ushort_t* BT = (blockIdx.z == 0) ? WqT : (blockIdx.z == 1) ? WkT : WvT;
    ushort_t* C        = (blockIdx.z == 0) ? Qo  : (blockIdx.z == 1) ? Ko  : Vo;
    __shared__ __align__(16) ushort_t As[128 * 32];
    __shared__ __align__(16) ushort_t Bs[128 * 32];
    const int m0 = blockIdx.y * 128, n0 = blockIdx.x * 128;

    floatx4 acc[4][4] = {};
    gemm_tile(A, BT, m0, n0, As, Bs, acc);

    const int tid = threadIdx.x;
    const int w = tid >> 6, wm = (w >> 1) * 64, wn = (w & 1) * 64;
    const int lrow = tid & 15;
    const int rquad = ((tid & 63) >> 4) * 4;
#pragma unroll
    for (int i = 0; i < 4; ++i) {
        const int mbase = m0 + wm + i * 16 + rquad;
#pragma unroll
        for (int j = 0; j < 4; ++j) {
            const int gn = n0 + wn + j * 16 + lrow;
#pragma unroll
            for (int r = 0; r < 4; ++r)
                C[(size_t)(mbase + r) * D_DIM + gn] = f2bf(acc[i][j][r]);
        }
    }
}

// Output projection: f32 out = A @ Wo + bo.
__global__ __launch_bounds__(256, 2) void gemm_out_kernel(
        const ushort_t* __restrict__ A, const ushort_t* __restrict__ WoT,
        const float* __restrict__ bias, float* __restrict__ C) {
    __shared__ __align__(16) ushort_t As[128 * 32];
    __shared__ __align__(16) ushort_t Bs[128 * 32];
    const int m0 = blockIdx.y * 128, n0 = blockIdx.x * 128;

    floatx4 acc[4][4] = {};
    gemm_tile(A, WoT, m0, n0, As, Bs, acc);

    const int tid = threadIdx.x;
    const int w = tid >> 6, wm = (w >> 1) * 64, wn = (w & 1) * 64;
    const int lrow = tid & 15;
    const int rquad = ((tid & 63) >> 4) * 4;
#pragma unroll
    for (int i = 0; i < 4; ++i) {
        const int mbase = m0 + wm + i * 16 + rquad;
#pragma unroll
        for (int j = 0; j < 4; ++j) {
            const int gn = n0 + wn + j * 16 + lrow;
            const float badd = bias[gn];
#pragma unroll
            for (int r = 0; r < 4; ++r)
                C[(size_t)(mbase + r) * D_DIM + gn] = acc[i][j][r] + badd;
        }
    }
}

// ---------------------------------------------------------------- MFMA flash attention
// Q,K,V,O merged row-major [B*S, D] bf16; head h = channels h*64..h*64+63.
// R4: occupancy + balance rework. Grid (32 bh, 32 qtiles) = 1024 blocks
// (4 blocks/CU, 50% grid ceiling vs 25% before). Block q-tile = 64 rows,
// wave = 16 rows. 64-key tiles staged in LDS (K natural dword copies,
// V transposed via PAIR-PACKED dword stores: 2-way banks = free).
// S = Q K^T via 16x16x32 MFMA; online softmax on C-layout; P -> LDS (bf16)
// -> A-frags; O += P V via MFMA. LDS rows stride 33 dwords (66 bf16).
__global__ __launch_bounds__(256, 4) void attn_mfma_kernel(
        const ushort_t* __restrict__ Q, const ushort_t* __restrict__ K,
        const ushort_t* __restrict__ V, ushort_t* __restrict__ O) {
    __shared__ uint_t Ks32[64 * 33];       // [key][d-pairs]
    __shared__ uint_t Vt32[64 * 33];       // [d][key-pairs] (transposed V)
    __shared__ uint_t Ps32[4][16 * 33];    // per-wave P [row][key-pairs]

    const int bh  = blockIdx.x;
    const int b   = bh >> 4, h = bh & 15;
    const int qt  = 31 - (int)blockIdx.y;   // biggest work first
    const int q0  = qt * 64;
    const int tid = threadIdx.x;
    const int wq  = tid >> 6;
    const int lane = tid & 63;
    const int col  = lane & 15;
    const int quad = lane >> 4;
    const int qw0  = q0 + wq * 16;          // wave's first q-row
    const size_t rowbase = (size_t)b * S_LEN;
    const int ch0 = h * HD;

    // Q A-fragments: A[m = qrow][k = d]; lane holds A[m=col][k=quad*8+e]
    short8 aq[2];
#pragma unroll
    for (int kc = 0; kc < 2; ++kc)
        aq[kc] = *(const short8*)(Q + (rowbase + qw0 + col) * D_DIM
                                    + ch0 + kc * 32 + quad * 8);

    floatx4 oacc[4] = {};
    float mrun[4], lrun[4];
#pragma unroll
    for (int r = 0; r < 4; ++r) { mrun[r] = -1e30f; lrun[r] = 0.0f; }

    const int ntiles = qt + 1;
    // K staging: thread = (key, d-chunk-of-16)
    const int skey = tid >> 2;           // 0..63
    const int schk = tid & 3;            // 0..3
    // V staging: thread = (key-pair, d-chunk-of-8)
    const int kp = tid >> 3;             // 0..31
    const int dc = tid & 7;              // 0..7

    for (int t = 0; t < ntiles; ++t) {
        const int kb = t * 64;
        __syncthreads();   // previous tile's LDS reads complete
        // ---- stage K tile (dword copies, natural [key][d])
        {
            const uint_t* kg = (const uint_t*)(K + (rowbase + kb + skey) * D_DIM + ch0 + schk * 16);
            const uint4 u0 = *(const uint4*)(kg);
            const uint4 u1 = *(const uint4*)(kg + 4);
            uint_t* kd = Ks32 + skey * 33 + schk * 8;
            kd[0] = u0.x; kd[1] = u0.y; kd[2] = u0.z; kd[3] = u0.w;
            kd[4] = u1.x; kd[5] = u1.y; kd[6] = u1.z; kd[7] = u1.w;
        }
        // ---- stage V tile transposed, pair-packed: Vt[d][keypair] dword stores
        {
            const ushort_t* vg0 = V + (rowbase + kb + 2 * kp) * D_DIM + ch0 + dc * 8;
            const short8 v0 = *(const short8*)(vg0);
            const short8 v1 = *(const short8*)(vg0 + D_DIM);
            uint_t* vt = Vt32 + kp;
#pragma unroll
            for (int e = 0; e < 8; ++e) {
                const uint_t lo = (uint_t)(ushort_t)v0[e];
                const uint_t hi = (uint_t)(ushort_t)v1[e];
                vt[(dc * 8 + e) * 33] = lo | (hi << 16);
            }
        }
        __syncthreads();

        if (kb <= qw0 + 15) {            // wave-uniform: tile has valid keys for this wave
            // ---- S = Q K^T
            floatx4 sa[4] = {};
            __builtin_amdgcn_s_setprio(1);
#pragma unroll
            for (int kc = 0; kc < 2; ++kc)
#pragma unroll
                for (int j = 0; j < 4; ++j) {
                    union { short8 s; uint_t u[4]; } bk;
                    const uint_t* kp_ = Ks32 + (j * 16 + col) * 33 + kc * 16 + quad * 4;
                    bk.u[0] = kp_[0]; bk.u[1] = kp_[1]; bk.u[2] = kp_[2]; bk.u[3] = kp_[3];
                    sa[j] = __builtin_amdgcn_mfma_f32_16x16x32_bf16(
                        aq[kc], bk.s, sa[j], 0, 0, 0);
                }
            __builtin_amdgcn_s_setprio(0);

            const bool needmask = (kb + 63 > qw0);
            // ---- scale + causal mask
#pragma unroll
            for (int j = 0; j < 4; ++j)
#pragma unroll
                for (int r = 0; r < 4; ++r) {
                    float v = sa[j][r] * 0.125f;
                    if (needmask) {
                        const int row = qw0 + quad * 4 + r;
                        const int key = kb + j * 16 + col;
                        v = (key <= row) ? v : -1e30f;
                    }
                    sa[j][r] = v;
                }
            // ---- online softmax per row (row = quad*4 + r; cols across lanes)
#pragma unroll
            for (int r = 0; r < 4; ++r) {
                float mx = fmaxf(fmaxf(sa[0][r], sa[1][r]),
                                 fmaxf(sa[2][r], sa[3][r]));
                mx = fmaxf(mx, __shfl_xor(mx, 1));
                mx = fmaxf(mx, __shfl_xor(mx, 2));
                mx = fmaxf(mx, __shfl_xor(mx, 4));
                mx = fmaxf(mx, __shfl_xor(mx, 8));
                const float mn = fmaxf(mrun[r], mx);
                const float al = __expf(mrun[r] - mn);
                mrun[r] = mn;
                float rs = 0.0f;
#pragma unroll
                for (int j = 0; j < 4; ++j) {
                    const float p = __expf(sa[j][r] - mn);
                    sa[j][r] = p;
                    rs += p;
                }
                rs += __shfl_xor(rs, 1);
                rs += __shfl_xor(rs, 2);
                rs += __shfl_xor(rs, 4);
                rs += __shfl_xor(rs, 8);
                lrun[r] = lrun[r] * al + rs;
#pragma unroll
                for (int jd = 0; jd < 4; ++jd) oacc[jd][r] *= al;
            }
            // ---- write P (bf16) to this wave's LDS region
            {
                ushort_t* pw = (ushort_t*)Ps32[wq];
#pragma unroll
                for (int j = 0; j < 4; ++j)
#pragma unroll
                    for (int r = 0; r < 4; ++r)
                        pw[(quad * 4 + r) * 66 + j * 16 + col] = f2bf(sa[j][r]);
            }
            asm volatile("s_waitcnt lgkmcnt(0)" ::: "memory");   // wave-local RAW
            // ---- O += P V
            __builtin_amdgcn_s_setprio(1);
#pragma unroll
            for (int kc = 0; kc < 2; ++kc) {
                union { short8 s; uint_t u[4]; } ap;
                const uint_t* pp = Ps32[wq] + col * 33 + kc * 16 + quad * 4;
                ap.u[0] = pp[0]; ap.u[1] = pp[1]; ap.u[2] = pp[2]; ap.u[3] = pp[3];
#pragma unroll
                for (int jd = 0; jd < 4; ++jd) {
                    union { short8 s; uint_t u[4]; } bv;
                    const uint_t* vp = Vt32 + (jd * 16 + col) * 33 + kc * 16 + quad * 4;
                    bv.u[0] = vp[0]; bv.u[1] = vp[1]; bv.u[2] = vp[2]; bv.u[3] = vp[3];
                    oacc[jd] = __builtin_amdgcn_mfma_f32_16x16x32_bf16(
                        ap.s, bv.s, oacc[jd], 0, 0, 0);
                }
            }
            __builtin_amdgcn_s_setprio(0);
        }
    }

    // ---- epilogue: O row-major bf16, normalized
#pragma unroll
    for (int r = 0; r < 4; ++r) {
        const int row = qw0 + quad * 4 + r;
        const float inv = 1.0f / lrun[r];
#pragma unroll
        for (int jd = 0; jd < 4; ++jd)
            O[(rowbase + row) * D_DIM + ch0 + jd * 16 + col] =
                f2bf(oacc[jd][r] * inv);
    }
}

// ---------------------------------------------------------------- launch
extern "C" void kernel_launch(void* const* d_in, const int* in_sizes, int n_in,
                              void* d_out, int out_size, void* d_ws, size_t ws_size,
                              hipStream_t stream) {
    const float* x  = (const float*)d_in[0];
    const float* Wq = (const float*)d_in[1];
    const float* Wk = (const float*)d_in[2];
    const float* Wv = (const float*)d_in[3];
    const float* Wo = (const float*)d_in[4];
    const float* bo = (const float*)d_in[5];
    float* out = (float*)d_out;                // f32 output

    char* ws = (char*)d_ws;
    const size_t MB = 1024 * 1024;
    ushort_t* xb  = (ushort_t*)(ws + 0 * MB);   // 8 MB
    ushort_t* WqT = (ushort_t*)(ws + 8 * MB);   // 2 MB each
    ushort_t* WkT = (ushort_t*)(ws + 10 * MB);
    ushort_t* WvT = (ushort_t*)(ws + 12 * MB);
    ushort_t* WoT = (ushort_t*)(ws + 14 * MB);
    ushort_t* Qb  = (ushort_t*)(ws + 16 * MB);  // [B*S, D] bf16, 8 MB each
    ushort_t* Kb  = (ushort_t*)(ws + 24 * MB);
    ushort_t* Vb  = (ushort_t*)(ws + 32 * MB);
    ushort_t* Ob  = (ushort_t*)(ws + 40 * MB);  // total 48 MB

    cast_x_kernel<<<4096, 256, 0, stream>>>(x, xb);
    transpose4_kernel<<<dim3(16, 16, 4), 256, 0, stream>>>(
        Wq, Wk, Wv, Wo, WqT, WkT, WvT, WoT);

    gemm_qkv_kernel<<<dim3(8, 32, 3), 256, 0, stream>>>(
        xb, WqT, WkT, WvT, Qb, Kb, Vb);

    attn_mfma_kernel<<<dim3(32, 32), 256, 0, stream>>>(Qb, Kb, Vb, Ob);

    gemm_out_kernel<<<dim3(8, 32), 256, 0, stream>>>(Ob, WoT, bo, out);
}

// Round 2
// 219.043 us; speedup vs baseline: 1.1948x; 1.0949x over previous
//
#include <hip/hip_runtime.h>

typedef unsigned short ushort_t;
typedef unsigned int uint_t;
typedef __attribute__((ext_vector_type(8))) short short8;
typedef __attribute__((ext_vector_type(4))) float floatx4;

#define S_LEN 2048
#define D_DIM 1024
#define H_NUM 16
#define HD 64

__device__ __forceinline__ float bf2f(ushort_t u) {
    union { uint_t i; float f; } c; c.i = ((uint_t)u) << 16; return c.f;
}
__device__ __forceinline__ ushort_t f2bf(float f) {
    union { float f; uint_t i; } c; c.f = f;
    uint_t r = c.i + 0x7fffu + ((c.i >> 16) & 1u);
    return (ushort_t)(r >> 16);
}

// ---------------------------------------------------------------- cast x
__global__ __launch_bounds__(256, 4) void cast_x_kernel(
        const float* __restrict__ in, ushort_t* __restrict__ out) {
    const int idx = (blockIdx.x * 256 + threadIdx.x) * 4;
    const float4 v = *(const float4*)(in + idx);
    ushort4 o;
    o.x = f2bf(v.x); o.y = f2bf(v.y); o.z = f2bf(v.z); o.w = f2bf(v.w);
    *(ushort4*)(out + idx) = o;
}

// ---------------------------------------------------------------- transpose+cast (validated R3)
__global__ __launch_bounds__(256, 2) void transpose4_kernel(
        const float* __restrict__ W0, const float* __restrict__ W1,
        const float* __restrict__ W2, const float* __restrict__ W3,
        ushort_t* __restrict__ T0, ushort_t* __restrict__ T1,
        ushort_t* __restrict__ T2, ushort_t* __restrict__ T3) {
    const int z = blockIdx.z;
    const float* in  = (z == 0) ? W0 : (z == 1) ? W1 : (z == 2) ? W2 : W3;
    ushort_t*    out = (z == 0) ? T0 : (z == 1) ? T1 : (z == 2) ? T2 : T3;
    __shared__ __align__(16) ushort_t t[64][65];
    const int r0 = blockIdx.y * 64, c0 = blockIdx.x * 64;
    const int tr = threadIdx.x >> 4;
    const int tc = (threadIdx.x & 15) * 4;
#pragma unroll
    for (int i = 0; i < 4; ++i) {
        const int row = tr + i * 16;
        const float4 v = *(const float4*)(in + (size_t)(r0 + row) * D_DIM + c0 + tc);
        t[row][tc + 0] = f2bf(v.x); t[row][tc + 1] = f2bf(v.y);
        t[row][tc + 2] = f2bf(v.z); t[row][tc + 3] = f2bf(v.w);
    }
    __syncthreads();
#pragma unroll
    for (int i = 0; i < 4; ++i) {
        const int n = tr + i * 16;
        ushort4 v;
        v.x = t[tc + 0][n]; v.y = t[tc + 1][n];
        v.z = t[tc + 2][n]; v.w = t[tc + 3][n];
        *(ushort4*)(out + (size_t)(c0 + n) * D_DIM + r0 + tc) = v;
    }
}

// ---------------------------------------------------------------- MFMA GEMM tile (validated R3)
// C[M,N] = A[M,K] @ B with BT = B^T [N,K] row-major. 128x128 tile, BK=32,
// 4 waves 2x2 of 64x64, 16x16x32 bf16 MFMA, register->LDS staging.
__device__ __forceinline__ void gemm_tile(
        const ushort_t* __restrict__ A, const ushort_t* __restrict__ BT,
        const int m0, const int n0,
        ushort_t* As, ushort_t* Bs, floatx4 acc[4][4]) {
    const int tid  = threadIdx.x;
    const int w    = tid >> 6;
    const int wm   = (w >> 1) * 64;
    const int wn   = (w & 1) * 64;
    const int lrow = tid & 15;
    const int kq   = ((tid & 63) >> 4) * 8;

    const int flat0 = tid * 8;
    const int flat1 = (256 + tid) * 8;
    const int row0 = flat0 >> 5, kk0 = flat0 & 31;
    const int row1 = flat1 >> 5, kk1 = flat1 & 31;

    for (int k0 = 0; k0 < D_DIM; k0 += 32) {
        const short8 a0 = *(const short8*)(A  + (size_t)(m0 + row0) * D_DIM + k0 + kk0);
        const short8 b0 = *(const short8*)(BT + (size_t)(n0 + row0) * D_DIM + k0 + kk0);
        const short8 a1 = *(const short8*)(A  + (size_t)(m0 + row1) * D_DIM + k0 + kk1);
        const short8 b1 = *(const short8*)(BT + (size_t)(n0 + row1) * D_DIM + k0 + kk1);
        __syncthreads();
        *(short8*)(As + flat0) = a0; *(short8*)(Bs + flat0) = b0;
        *(short8*)(As + flat1) = a1; *(short8*)(Bs + flat1) = b1;
        __syncthreads();

        short8 av[4], bv[4];
#pragma unroll
        for (int i = 0; i < 4; ++i)
            av[i] = *(const short8*)(As + (wm + i * 16 + lrow) * 32 + kq);
#pragma unroll
        for (int j = 0; j < 4; ++j)
            bv[j] = *(const short8*)(Bs + (wn + j * 16 + lrow) * 32 + kq);
#pragma unroll
        for (int i = 0; i < 4; ++i)
#pragma unroll
            for (int j = 0; j < 4; ++j)
                acc[i][j] = __builtin_amdgcn_mfma_f32_16x16x32_bf16(
                    av[i], bv[j], acc[i][j], 0, 0, 0);
    }
}

// QKV: z picks weight/dest; writes merged row-major [B*S, D] bf16.
__global__ __launch_bounds__(256, 2) void gemm_qkv_kernel(
        const ushort_t* __restrict__ A,
        const ushort_t* __restrict__ WqT, const ushort_t* __restrict__ WkT,
        const ushort_t* __restrict__ WvT,
        ushort_t* __restrict__ Qo, ushort_t* __restrict__ Ko,
        ushort_t* __restrict__ Vo) {
    const ushort_t* BT = (blockIdx.z == 0) ? WqT : (blockIdx.z == 1) ? WkT : WvT;
    ushort_t* C        = (blockIdx.z == 0) ? Qo  : (blockIdx.z == 1) ? Ko  : Vo;
    __shared__ __align__(16) ushort_t As[128 * 32];
    __shared__ __align__(16) ushort_t Bs[128 * 32];
    const int m0 = blockIdx.y * 128, n0 = blockIdx.x * 128;

    floatx4 acc[4][4] = {};
    gemm_tile(A, BT, m0, n0, As, Bs, acc);

    const int tid = threadIdx.x;
    const int w = tid >> 6, wm = (w >> 1) * 64, wn = (w & 1) * 64;
    const int lrow = tid & 15;
    const int rquad = ((tid & 63) >> 4) * 4;
#pragma unroll
    for (int i = 0; i < 4; ++i) {
        const int mbase = m0 + wm + i * 16 + rquad;
#pragma unroll
        for (int j = 0; j < 4; ++j) {
            const int gn = n0 + wn + j * 16 + lrow;
#pragma unroll
            for (int r = 0; r < 4; ++r)
                C[(size_t)(mbase + r) * D_DIM + gn] = f2bf(acc[i][j][r]);
        }
    }
}

// Output projection: f32 out = A @ Wo + bo.
__global__ __launch_bounds__(256, 2) void gemm_out_kernel(
        const ushort_t* __restrict__ A, const ushort_t* __restrict__ WoT,
        const float* __restrict__ bias, float* __restrict__ C) {
    __shared__ __align__(16) ushort_t As[128 * 32];
    __shared__ __align__(16) ushort_t Bs[128 * 32];
    const int m0 = blockIdx.y * 128, n0 = blockIdx.x * 128;

    floatx4 acc[4][4] = {};
    gemm_tile(A, WoT, m0, n0, As, Bs, acc);

    const int tid = threadIdx.x;
    const int w = tid >> 6, wm = (w >> 1) * 64, wn = (w & 1) * 64;
    const int lrow = tid & 15;
    const int rquad = ((tid & 63) >> 4) * 4;
#pragma unroll
    for (int i = 0; i < 4; ++i) {
        const int mbase = m0 + wm + i * 16 + rquad;
#pragma unroll
        for (int j = 0; j < 4; ++j) {
            const int gn = n0 + wn + j * 16 + lrow;
            const float badd = bias[gn];
#pragma unroll
            for (int r = 0; r < 4; ++r)
                C[(size_t)(mbase + r) * D_DIM + gn] = acc[i][j][r] + badd;
        }
    }
}

// ---------------------------------------------------------------- MFMA flash attention
// Q,K,V,O merged row-major [B*S, D] bf16; head h = channels h*64..h*64+63.
// R5: conflict-free swizzled LDS (m214 recipe). All tiles are linear
// [rows][64] bf16 (128 B rows) with XOR swizzle idx = r*64 + (c ^ ((r&7)<<3)).
// Every MFMA fragment is ONE ds_read_b128 at the b128 bank minimum
// (8 lanes/16B-granule). K staged 2x16B/thread; V staged transposed with
// pair-packed dword stores (32 banks x 2 = free). Grid (32 bh, 32 qtiles),
// 64-row q-tile, wave = 16 rows. Online softmax on C-layout.
__global__ __launch_bounds__(256, 4) void attn_mfma_kernel(
        const ushort_t* __restrict__ Q, const ushort_t* __restrict__ K,
        const ushort_t* __restrict__ V, ushort_t* __restrict__ O) {
    __shared__ __align__(16) ushort_t Ks[64 * 64];      // [key][d] swizzled
    __shared__ __align__(16) ushort_t Vt[64 * 64];      // [d][key] swizzled
    __shared__ __align__(16) ushort_t Ps[4][16 * 64];   // per-wave P [row][key] swizzled

    const int bh  = blockIdx.x;
    const int b   = bh >> 4, h = bh & 15;
    const int qt  = 31 - (int)blockIdx.y;   // biggest work first
    const int q0  = qt * 64;
    const int tid = threadIdx.x;
    const int wq  = tid >> 6;
    const int lane = tid & 63;
    const int col  = lane & 15;
    const int quad = lane >> 4;
    const int qw0  = q0 + wq * 16;          // wave's first q-row
    const size_t rowbase = (size_t)b * S_LEN;
    const int ch0 = h * HD;
    const int c7 = col & 7;

    // Q A-fragments: A[m = qrow][k = d]; lane holds A[m=col][k=quad*8+e]
    short8 aq[2];
#pragma unroll
    for (int kc = 0; kc < 2; ++kc)
        aq[kc] = *(const short8*)(Q + (rowbase + qw0 + col) * D_DIM
                                    + ch0 + kc * 32 + quad * 8);

    floatx4 oacc[4] = {};
    float mrun[4], lrun[4];
#pragma unroll
    for (int r = 0; r < 4; ++r) { mrun[r] = -1e30f; lrun[r] = 0.0f; }

    const int ntiles = qt + 1;
    // K staging: thread = (key, 32B d-chunk)
    const int skey = tid >> 2;           // 0..63
    const int schk = tid & 3;            // 0..3
    // V staging: thread = (key-pair, 8-wide d-chunk); kp spans 0..31 per wave
    const int vkp = tid & 31;            // key-pair 0..31
    const int vdc = tid >> 5;            // d-chunk 0..7

    for (int t = 0; t < ntiles; ++t) {
        const int kb = t * 64;
        __syncthreads();   // previous tile's LDS reads complete
        // ---- stage K tile: [key][d] bf16, swizzled 16B granules (conflict-free)
        {
            const ushort_t* kg = K + (rowbase + kb + skey) * D_DIM + ch0 + schk * 16;
            const short8 k0 = *(const short8*)(kg);
            const short8 k1 = *(const short8*)(kg + 8);
            const int sw = skey & 7;
            *(short8*)(Ks + skey * 64 + (((2 * schk) ^ sw) << 3)) = k0;
            *(short8*)(Ks + skey * 64 + (((2 * schk + 1) ^ sw) << 3)) = k1;
        }
        // ---- stage V tile transposed, pair-packed dword stores (32 banks x2 = free)
        {
            const ushort_t* vg = V + (rowbase + kb + 2 * vkp) * D_DIM + ch0 + vdc * 8;
            const short8 v0 = *(const short8*)(vg);
            const short8 v1 = *(const short8*)(vg + D_DIM);
#pragma unroll
            for (int e = 0; e < 8; ++e) {
                const int d = vdc * 8 + e;
                const uint_t pk = (uint_t)(ushort_t)v0[e] | ((uint_t)(ushort_t)v1[e] << 16);
                *(uint_t*)(Vt + d * 64 + ((2 * vkp) ^ ((d & 7) << 3))) = pk;
            }
        }
        __syncthreads();

        if (kb <= qw0 + 15) {            // wave-uniform: tile has valid keys for this wave
            // ---- S = Q K^T (B-frag: one ds_read_b128 per fragment, conflict-free)
            floatx4 sa[4] = {};
            __builtin_amdgcn_s_setprio(1);
#pragma unroll
            for (int kc = 0; kc < 2; ++kc)
#pragma unroll
                for (int j = 0; j < 4; ++j) {
                    const short8 bk = *(const short8*)(
                        Ks + (j * 16 + col) * 64 + (((kc * 4 + quad) ^ c7) << 3));
                    sa[j] = __builtin_amdgcn_mfma_f32_16x16x32_bf16(
                        aq[kc], bk, sa[j], 0, 0, 0);
                }
            __builtin_amdgcn_s_setprio(0);

            const bool needmask = (kb + 63 > qw0);
            // ---- scale + causal mask
#pragma unroll
            for (int j = 0; j < 4; ++j)
#pragma unroll
                for (int r = 0; r < 4; ++r) {
                    float v = sa[j][r] * 0.125f;
                    if (needmask) {
                        const int row = qw0 + quad * 4 + r;
                        const int key = kb + j * 16 + col;
                        v = (key <= row) ? v : -1e30f;
                    }
                    sa[j][r] = v;
                }
            // ---- online softmax per row (row = quad*4 + r; cols across lanes)
#pragma unroll
            for (int r = 0; r < 4; ++r) {
                float mx = fmaxf(fmaxf(sa[0][r], sa[1][r]),
                                 fmaxf(sa[2][r], sa[3][r]));
                mx = fmaxf(mx, __shfl_xor(mx, 1));
                mx = fmaxf(mx, __shfl_xor(mx, 2));
                mx = fmaxf(mx, __shfl_xor(mx, 4));
                mx = fmaxf(mx, __shfl_xor(mx, 8));
                const float mn = fmaxf(mrun[r], mx);
                const float al = __expf(mrun[r] - mn);
                mrun[r] = mn;
                float rs = 0.0f;
#pragma unroll
                for (int j = 0; j < 4; ++j) {
                    const float p = __expf(sa[j][r] - mn);
                    sa[j][r] = p;
                    rs += p;
                }
                rs += __shfl_xor(rs, 1);
                rs += __shfl_xor(rs, 2);
                rs += __shfl_xor(rs, 4);
                rs += __shfl_xor(rs, 8);
                lrun[r] = lrun[r] * al + rs;
#pragma unroll
                for (int jd = 0; jd < 4; ++jd) oacc[jd][r] *= al;
            }
            // ---- write P (bf16) to this wave's swizzled LDS region
            {
                ushort_t* pw = Ps[wq];
#pragma unroll
                for (int j = 0; j < 4; ++j)
#pragma unroll
                    for (int r = 0; r < 4; ++r) {
                        const int row = quad * 4 + r;
                        pw[row * 64 + ((j * 16 + col) ^ ((row & 7) << 3))] =
                            f2bf(sa[j][r]);
                    }
            }
            asm volatile("s_waitcnt lgkmcnt(0)" ::: "memory");   // wave-local RAW
            // ---- O += P V (A/B frags: one ds_read_b128 each, conflict-free)
            __builtin_amdgcn_s_setprio(1);
#pragma unroll
            for (int kc = 0; kc < 2; ++kc) {
                const short8 ap = *(const short8*)(
                    Ps[wq] + col * 64 + (((kc * 4 + quad) ^ c7) << 3));
#pragma unroll
                for (int jd = 0; jd < 4; ++jd) {
                    const short8 bv = *(const short8*)(
                        Vt + (jd * 16 + col) * 64 + (((kc * 4 + quad) ^ c7) << 3));
                    oacc[jd] = __builtin_amdgcn_mfma_f32_16x16x32_bf16(
                        ap, bv, oacc[jd], 0, 0, 0);
                }
            }
            __builtin_amdgcn_s_setprio(0);
        }
    }

    // ---- epilogue: O row-major bf16, normalized
#pragma unroll
    for (int r = 0; r < 4; ++r) {
        const int row = qw0 + quad * 4 + r;
        const float inv = 1.0f / lrun[r];
#pragma unroll
        for (int jd = 0; jd < 4; ++jd)
            O[(rowbase + row) * D_DIM + ch0 + jd * 16 + col] =
                f2bf(oacc[jd][r] * inv);
    }
}

// ---------------------------------------------------------------- launch
extern "C" void kernel_launch(void* const* d_in, const int* in_sizes, int n_in,
                              void* d_out, int out_size, void* d_ws, size_t ws_size,
                              hipStream_t stream) {
    const float* x  = (const float*)d_in[0];
    const float* Wq = (const float*)d_in[1];
    const float* Wk = (const float*)d_in[2];
    const float* Wv = (const float*)d_in[3];
    const float* Wo = (const float*)d_in[4];
    const float* bo = (const float*)d_in[5];
    float* out = (float*)d_out;                // f32 output

    char* ws = (char*)d_ws;
    const size_t MB = 1024 * 1024;
    ushort_t* xb  = (ushort_t*)(ws + 0 * MB);   // 8 MB
    ushort_t* WqT = (ushort_t*)(ws + 8 * MB);   // 2 MB each
    ushort_t* WkT = (ushort_t*)(ws + 10 * MB);
    ushort_t* WvT = (ushort_t*)(ws + 12 * MB);
    ushort_t* WoT = (ushort_t*)(ws + 14 * MB);
    ushort_t* Qb  = (ushort_t*)(ws + 16 * MB);  // [B*S, D] bf16, 8 MB each
    ushort_t* Kb  = (ushort_t*)(ws + 24 * MB);
    ushort_t* Vb  = (ushort_t*)(ws + 32 * MB);
    ushort_t* Ob  = (ushort_t*)(ws + 40 * MB);  // total 48 MB

    cast_x_kernel<<<4096, 256, 0, stream>>>(x, xb);
    transpose4_kernel<<<dim3(16, 16, 4), 256, 0, stream>>>(
        Wq, Wk, Wv, Wo, WqT, WkT, WvT, WoT);

    gemm_qkv_kernel<<<dim3(8, 32, 3), 256, 0, stream>>>(
        xb, WqT, WkT, WvT, Qb, Kb, Vb);

    attn_mfma_kernel<<<dim3(32, 32), 256, 0, stream>>>(Qb, Kb, Vb, Ob);

    gemm_out_kernel<<<dim3(8, 32), 256, 0, stream>>>(Ob, WoT, bo, out);
}